// Round 9
// baseline (186.861 us; speedup 1.0000x reference)
//
#include <hip/hip_runtime.h>
#include <hip/hip_bf16.h>
#include <math.h>

typedef __attribute__((ext_vector_type(8))) short short8;
typedef __attribute__((ext_vector_type(4))) float f32x4;
typedef __attribute__((ext_vector_type(4))) short short4v;
typedef __attribute__((ext_vector_type(2))) int int2v;

static __device__ __forceinline__ short f2bf(float f) {
    __hip_bfloat16 h = __float2bfloat16(f);
    return *reinterpret_cast<short*>(&h);
}
static __device__ __forceinline__ void store_out(float* p, float v) { *p = v; }
static __device__ __forceinline__ void store_out(short* p, float v) { *p = f2bf(v); }

#define GLL16(g, l) __builtin_amdgcn_global_load_lds( \
    (const __attribute__((address_space(1))) void*)(g), \
    (__attribute__((address_space(3))) void*)(l), 16, 0, 0)

#if __has_builtin(__builtin_amdgcn_exp2f)
#define EXP2(x) __builtin_amdgcn_exp2f(x)
#else
#define EXP2(x) exp2f(x)
#endif

// pack two f32 -> packed bf16 pair (low = a, high = b)
#if __has_builtin(__builtin_amdgcn_cvt_pk_bf16_f32)
typedef __attribute__((ext_vector_type(2))) __bf16 bf16x2;
static __device__ __forceinline__ int pack2bf(float a, float b) {
    bf16x2 r = __builtin_amdgcn_cvt_pk_bf16_f32(a, b);
    return __builtin_bit_cast(int, r);
}
#else
static __device__ __forceinline__ int pack2bf(float a, float b) {
    unsigned ua = __builtin_bit_cast(unsigned, a) + 0x8000u;
    unsigned ub = __builtin_bit_cast(unsigned, b) + 0x8000u;
    return (int)((ua >> 16) | (ub & 0xFFFF0000u));
}
#endif

// ---------------- fused prep: cast x -> bf16; transpose+cast both weights ----
static __device__ __forceinline__ void transpose_cast_tile(
    const float* __restrict__ W, short* __restrict__ Wt, int Kd, int N,
    int bx, int by)
{
    __shared__ float ts[32][33];
    const int c0 = bx * 32, r0 = by * 32;
    const int tx = threadIdx.x & 31, ty = threadIdx.x >> 5;   // ty 0..7
    #pragma unroll
    for (int e = 0; e < 4; ++e)
        ts[ty + e * 8][tx] = W[(size_t)(r0 + ty + e * 8) * N + c0 + tx];
    __syncthreads();
    #pragma unroll
    for (int e = 0; e < 4; ++e)
        Wt[(size_t)(c0 + ty + e * 8) * Kd + r0 + tx] = f2bf(ts[tx][ty + e * 8]);
}

__global__ __launch_bounds__(256) void prep_kernel(
    const float* __restrict__ x,      short* __restrict__ xb,    int nx,
    const float* __restrict__ W_qkv,  short* __restrict__ Wt1,
    const float* __restrict__ W_proj, short* __restrict__ Wt2,
    int C)
{
    const int nbx = nx / 1024;
    const int nb1 = (3 * C / 32) * (C / 32);
    int bid = blockIdx.x;
    if (bid < nbx) {
        int i = (bid * 256 + threadIdx.x) * 4;
        float4 v = *(const float4*)(x + i);
        short4v o = { f2bf(v.x), f2bf(v.y), f2bf(v.z), f2bf(v.w) };
        *(short4v*)(xb + i) = o;
        return;
    }
    bid -= nbx;
    if (bid < nb1) {
        const int nc = 3 * C / 32;
        transpose_cast_tile(W_qkv, Wt1, C, 3 * C, bid % nc, bid / nc);
        return;
    }
    bid -= nb1;
    {
        const int nc = C / 32;
        transpose_cast_tile(W_proj, Wt2, C, C, bid % nc, bid / nc);
    }
}

// ---------------- fused QKV GEMM + fragment-pack epilogue --------------------
// (Round 7, proven -3.3us): Q blocks -> dense qb[M][C] scaled bf16; K/V blocks
// stage the 128x128 tile in LDS (K token-major, V feat-major) then emit the
// fragment-packed kvp with contiguous 16B LDS reads + coalesced 1KB writes.
// Staging LDS unions with As/Bs (dead after K-loop). kvp layout = flash loads:
// kvp[bh][ci][f][lane*8sh], f 0..3 = K(nb*2+half), f 4..7 = V(db).
#define GK 32

__global__ __launch_bounds__(256) void gemm_qkv_kernel(
    const short* __restrict__ A, const short* __restrict__ Bt,
    const float* __restrict__ bias,
    short* __restrict__ qb, short* __restrict__ kvp,
    int M, int N, int Kd, int C, int Ktok, float qscale)
{
    __shared__ __attribute__((aligned(16))) short smem[17408];  // 34.8KB union
    short* As = smem;            // [128*32], K-loop only
    short* Bs = smem + 4096;     // [128*32], K-loop only
    short* T  = smem;            // [128][136] epilogue staging (after barrier)

    const int tid  = threadIdx.x;
    const int lane = tid & 63, w = tid >> 6;
    const int col  = lane & 15, quad = lane >> 4;
    const int wm = (w & 1) * 64, wn = (w >> 1) * 64;
    const int row0 = blockIdx.y * 128, col0 = blockIdx.x * 128;

    const int sr = tid >> 2, scg = (tid & 3) * 8;
    const short* gA = A  + (size_t)(row0 + sr) * Kd + scg;
    const short* gB = Bt + (size_t)(col0 + sr) * Kd + scg;
    short* lA = As + sr * GK + scg;
    short* lB = Bs + sr * GK + scg;
    const size_t skip = (size_t)64 * Kd;

    f32x4 acc[4][4] = {};
    for (int k0 = 0; k0 < Kd; k0 += GK) {
        __syncthreads();
        GLL16(gA,        lA);
        GLL16(gA + skip, lA + 64 * GK);
        GLL16(gB,        lB);
        GLL16(gB + skip, lB + 64 * GK);
        gA += GK; gB += GK;
        __syncthreads();

        short8 aF[4], bF[4];
        #pragma unroll
        for (int mt = 0; mt < 4; ++mt)
            aF[mt] = *(const short8*)&As[(wm + mt * 16 + col) * GK + quad * 8];
        #pragma unroll
        for (int nt = 0; nt < 4; ++nt)
            bF[nt] = *(const short8*)&Bs[(wn + nt * 16 + col) * GK + quad * 8];
        #pragma unroll
        for (int mt = 0; mt < 4; ++mt)
            #pragma unroll
            for (int nt = 0; nt < 4; ++nt)
                acc[mt][nt] = __builtin_amdgcn_mfma_f32_16x16x32_bf16(aF[mt], bF[nt], acc[mt][nt], 0, 0, 0);
    }

    if (col0 < C) {
        // ---- Q epilogue: scaled bf16 -> dense qb[M][C] ----
        #pragma unroll
        for (int mt = 0; mt < 4; ++mt)
            #pragma unroll
            for (int i = 0; i < 4; ++i) {
                const size_t r = row0 + wm + mt * 16 + quad * 4 + i;
                #pragma unroll
                for (int nt = 0; nt < 4; ++nt) {
                    const int c = col0 + wn + nt * 16 + col;
                    qb[r * C + c] = f2bf((acc[mt][nt][i] + bias[c]) * qscale);
                }
            }
        return;
    }

    // ---- K/V epilogue: stage tile in LDS, emit fragment-packed kvp ----
    const bool isK = col0 < 2 * C;
    __syncthreads();                         // all waves done with As/Bs
    #pragma unroll
    for (int mt = 0; mt < 4; ++mt)
        #pragma unroll
        for (int i = 0; i < 4; ++i) {
            const int rr = wm + mt * 16 + quad * 4 + i;      // token_rel
            #pragma unroll
            for (int nt = 0; nt < 4; ++nt) {
                const int cr = wn + nt * 16 + col;           // feat_rel
                const short v = f2bf(acc[mt][nt][i] + bias[col0 + cr]);
                if (isK) T[rr * 136 + cr] = v;               // token-major
                else     T[cr * 136 + rr] = v;               // feat-major
            }
        }
    __syncthreads();

    const int bb  = row0 / Ktok, k0t = row0 % Ktok;
    const int h0  = (col0 - (isK ? C : 2 * C)) >> 6;         // 2 heads/block
    #pragma unroll
    for (int j = 0; j < 8; ++j) {
        const int s     = tid + j * 256;                     // 0..2047
        const int lane2 = s & 63, f = (s >> 6) & 3, cil = (s >> 8) & 3, hl = s >> 10;
        const int col2  = lane2 & 15, quad2 = lane2 >> 4;
        short8 d;
        if (isK) {   // K frag f=nb*2+half: K[2*col2+nb][half*32+quad2*8 ..+8]
            const int nb = f >> 1, half = f & 1;
            d = *(const short8*)&T[(cil * 32 + 2 * col2 + nb) * 136
                                   + hl * 64 + half * 32 + quad2 * 8];
        } else {     // V frag f=db: V[quad2*8+j'][db*16+col2] via transposed T
            d = *(const short8*)&T[(hl * 64 + f * 16 + col2) * 136
                                   + cil * 32 + quad2 * 8];
        }
        const int bh = bb * 16 + h0 + hl;
        const int ci = (k0t >> 5) + cil;
        const int fr = isK ? f : 4 + f;
        *(short8*)(kvp + (((size_t)bh * 64 + ci) * 8 + fr) * 512 + lane2 * 8) = d;
    }
}

// ---------------- MFMA bf16 GEMM (m97 structure): C = A @ Bt^T + bias --------
// Templated on tile (GM x GN). gemm3 at 128x64 -> 512 blocks = 2/CU (round 5).
template <typename OutT, int GM, int GN>
__global__ __launch_bounds__(256) void gemm_mfma_kernel(
    const short* __restrict__ A, const short* __restrict__ Bt,
    const float* __restrict__ bias, OutT* __restrict__ C,
    int M, int N, int Kd)
{
    constexpr int WM = GM / 2, WN = GN / 2;      // per-wave quadrant
    __shared__ __attribute__((aligned(16))) short As[GM * GK];
    __shared__ __attribute__((aligned(16))) short Bs[GN * GK];
    const int tid  = threadIdx.x;
    const int lane = tid & 63, w = tid >> 6;
    const int col  = lane & 15, quad = lane >> 4;
    const int wm = (w & 1) * WM, wn = (w >> 1) * WN;
    const int row0 = blockIdx.y * GM, col0 = blockIdx.x * GN;

    const int sr = tid >> 2, scg = (tid & 3) * 8;   // 256 threads cover 64 rows x GK
    const short* gA = A  + (size_t)(row0 + sr) * Kd + scg;
    const short* gB = Bt + (size_t)(col0 + sr) * Kd + scg;
    short* lA = As + sr * GK + scg;
    short* lB = Bs + sr * GK + scg;
    const size_t skip = (size_t)64 * Kd;

    f32x4 acc[WM / 16][WN / 16] = {};
    for (int k0 = 0; k0 < Kd; k0 += GK) {
        __syncthreads();
        #pragma unroll
        for (int t = 0; t < GM / 64; ++t) GLL16(gA + t * skip, lA + t * 64 * GK);
        #pragma unroll
        for (int t = 0; t < GN / 64; ++t) GLL16(gB + t * skip, lB + t * 64 * GK);
        gA += GK; gB += GK;
        __syncthreads();

        short8 aF[WM / 16], bF[WN / 16];
        #pragma unroll
        for (int mt = 0; mt < WM / 16; ++mt)
            aF[mt] = *(const short8*)&As[(wm + mt * 16 + col) * GK + quad * 8];
        #pragma unroll
        for (int nt = 0; nt < WN / 16; ++nt)
            bF[nt] = *(const short8*)&Bs[(wn + nt * 16 + col) * GK + quad * 8];
        #pragma unroll
        for (int mt = 0; mt < WM / 16; ++mt)
            #pragma unroll
            for (int nt = 0; nt < WN / 16; ++nt)
                acc[mt][nt] = __builtin_amdgcn_mfma_f32_16x16x32_bf16(aF[mt], bF[nt], acc[mt][nt], 0, 0, 0);
    }

    #pragma unroll
    for (int mt = 0; mt < WM / 16; ++mt)
        #pragma unroll
        for (int i = 0; i < 4; ++i) {
            const size_t r = row0 + wm + mt * 16 + quad * 4 + i;
            #pragma unroll
            for (int nt = 0; nt < WN / 16; ++nt) {
                const int c = col0 + wn + nt * 16 + col;
                store_out(&C[r * N + c], acc[mt][nt][i] + bias[c]);
            }
        }
}

// ---------------- MFMA flash attention — K-prefetch, no lambdas --------------
// Rounds 6/7 postmortem isolated the scratch-demotion trigger: LAMBDA OUT-REFS
// writing LOOP-CARRIED aggregates (address-taken -> SROA fails). The pipeline
// idea survives when expressed demotion-proof:
//   - 8 plain named short8 vars; K prefetched UNCONDITIONALLY into the same
//     four vars with a clamped chunk index (min(ci+4,NC-1), always valid) --
//     old live range dies cleanly, no phi, ~0 extra registers.
//   - vmcnt in-order gives the pipeline free: S(i) waits only K(i) (issued a
//     full body ago -> covered), leaving V(i) in flight; PV(i) waits V(i),
//     leaving K(i+1) in flight.
//   - both qg P-writes batched before both P-reads: ONE exposed LDS
//     round-trip per body instead of two.
// Everything else round-4/8 verbatim: 32-q tiles, 2 qg/wave, 1024 blocks =
// 4/CU, pair-balanced (g, 63-g), pairwise reduction, LDS 17.4KB.
// Spill tell: VGPR must stay ~120-132; WRITE_SIZE ~8MB. Else revert + pivot.
#define DH 64

__global__ __launch_bounds__(256, 4) void flash_mfma_kernel(
    const short* __restrict__ qb,     // bf16 [B*K][C] Q only (pre-scaled)
    const short* __restrict__ kvp,    // fragment-packed K/V
    short* __restrict__ y,            // bf16 [B,K,C]
    int K, int C)
{
    // Or region (2 x 32 x 68 f32 = 17408B) aliases the P region (5120 sh):
    // P is live only during the chunk loop, Or only after the __syncthreads().
    __shared__ __attribute__((aligned(16))) short smem[8704];

    const int tid  = threadIdx.x;
    const int lane = tid & 63, w = tid >> 6;
    const int col  = lane & 15, quad = lane >> 4;

    short* Pw = smem + w * 1280;           // 2 qg bufs x 640 sh, wave-private

    const int cmb = blockIdx.x & 31;       // b*16+h  (XCD-local: idx%8 tracks h)
    const int g   = blockIdx.x >> 5;       // pair index 0..31
    const int b   = cmb >> 4, h = cmb & 15;

    short8 bOnes;                          // L = P @ ones-column = rowsum
    #pragma unroll
    for (int j = 0; j < 8; ++j) bOnes[j] = (col == 0) ? (short)0x3F80 : (short)0;

    const short* qbase  = qb + (size_t)b * K * C + h * DH;
    const short* kvbase = kvp + (size_t)cmb * 64 * 4096 + lane * 8;

    auto run = [&](int T) {
        const int t0 = T * 32;
        const int NC = T + 1;              // 32-key chunks in this tile
        const int NCm1 = NC - 1;

        short8 aQ[2][2];
        #pragma unroll
        for (int qg = 0; qg < 2; ++qg) {
            const short* qp = qbase + (size_t)(t0 + qg * 16 + col) * C;
            aQ[qg][0] = *(const short8*)(qp + quad * 8);
            aQ[qg][1] = *(const short8*)(qp + 32 + quad * 8);
        }
        f32x4 O[2][4] = {};
        f32x4 L4[2] = {};

        // prologue K for chunk w (clamped; unused if this wave has no chunks)
        short8 k00, k01, k10, k11;
        {
            const int c0 = (w < NC) ? w : NCm1;
            const short* p = kvbase + (size_t)c0 * 4096;
            k00 = *(const short8*)(p);
            k01 = *(const short8*)(p + 512);
            k10 = *(const short8*)(p + 1024);
            k11 = *(const short8*)(p + 1536);
        }

        for (int ci = w; ci < NC; ci += 4) {
            // V for this chunk: used by PV at body bottom (covered by S+exp)
            const short* pv = kvbase + (size_t)ci * 4096 + 2048;
            short8 v0 = *(const short8*)(pv);
            short8 v1 = *(const short8*)(pv + 512);
            short8 v2 = *(const short8*)(pv + 1024);
            short8 v3 = *(const short8*)(pv + 1536);

            const int kc = ci * 32;
            __builtin_amdgcn_s_setprio(1);

            // ---- S for both qg from k00..k11 (prefetched one body ago) ----
            f32x4 Sg[2][2] = {};
            #pragma unroll
            for (int qg = 0; qg < 2; ++qg) {
                Sg[qg][0] = __builtin_amdgcn_mfma_f32_16x16x32_bf16(aQ[qg][0], k00, Sg[qg][0], 0, 0, 0);
                Sg[qg][0] = __builtin_amdgcn_mfma_f32_16x16x32_bf16(aQ[qg][1], k01, Sg[qg][0], 0, 0, 0);
                Sg[qg][1] = __builtin_amdgcn_mfma_f32_16x16x32_bf16(aQ[qg][0], k10, Sg[qg][1], 0, 0, 0);
                Sg[qg][1] = __builtin_amdgcn_mfma_f32_16x16x32_bf16(aQ[qg][1], k11, Sg[qg][1], 0, 0, 0);
            }

            // ---- k-regs now dead: unconditional clamped prefetch (no phi) ----
            {
                int cn = ci + 4; if (cn > NCm1) cn = NCm1;
                const short* pn = kvbase + (size_t)cn * 4096;
                k00 = *(const short8*)(pn);
                k01 = *(const short8*)(pn + 512);
                k10 = *(const short8*)(pn + 1024);
                k11 = *(const short8*)(pn + 1536);
            }

            // ---- exp/mask + P-write for both qg ----
            #pragma unroll
            for (int qg = 0; qg < 2; ++qg) {
                const int qb2 = t0 + qg * 16;
                short* Ptq = Pw + qg * 640;
                if (kc + 31 <= qb2) {       // fully unmasked for this q-group
                    #pragma unroll
                    for (int i = 0; i < 4; ++i)
                        *(int*)&Ptq[(quad * 4 + i) * 40 + col * 2] =
                            pack2bf(EXP2(Sg[qg][0][i]), EXP2(Sg[qg][1][i]));
                } else {
                    const int kg = kc + col * 2;
                    #pragma unroll
                    for (int i = 0; i < 4; ++i) {
                        const int q = qb2 + quad * 4 + i;
                        float s0 = (kg + 0 <= q) ? Sg[qg][0][i] : -INFINITY;
                        float s1 = (kg + 1 <= q) ? Sg[qg][1][i] : -INFINITY;
                        *(int*)&Ptq[(quad * 4 + i) * 40 + col * 2] =
                            pack2bf(EXP2(s0), EXP2(s1));
                    }
                }
            }

            // ---- batched P-reads (one exposed LDS round-trip), then PVs ----
            short8 aP0 = *(const short8*)&Pw[col * 40 + quad * 8];
            short8 aP1 = *(const short8*)&Pw[640 + col * 40 + quad * 8];
            O[0][0] = __builtin_amdgcn_mfma_f32_16x16x32_bf16(aP0, v0, O[0][0], 0, 0, 0);
            O[0][1] = __builtin_amdgcn_mfma_f32_16x16x32_bf16(aP0, v1, O[0][1], 0, 0, 0);
            O[0][2] = __builtin_amdgcn_mfma_f32_16x16x32_bf16(aP0, v2, O[0][2], 0, 0, 0);
            O[0][3] = __builtin_amdgcn_mfma_f32_16x16x32_bf16(aP0, v3, O[0][3], 0, 0, 0);
            O[1][0] = __builtin_amdgcn_mfma_f32_16x16x32_bf16(aP1, v0, O[1][0], 0, 0, 0);
            O[1][1] = __builtin_amdgcn_mfma_f32_16x16x32_bf16(aP1, v1, O[1][1], 0, 0, 0);
            O[1][2] = __builtin_amdgcn_mfma_f32_16x16x32_bf16(aP1, v2, O[1][2], 0, 0, 0);
            O[1][3] = __builtin_amdgcn_mfma_f32_16x16x32_bf16(aP1, v3, O[1][3], 0, 0, 0);
            L4[0] = __builtin_amdgcn_mfma_f32_16x16x32_bf16(aP0, bOnes, L4[0], 0, 0, 0);
            L4[1] = __builtin_amdgcn_mfma_f32_16x16x32_bf16(aP1, bOnes, L4[1], 0, 0, 0);
            __builtin_amdgcn_s_setprio(0);
        }

        // ---- pairwise cross-wave reduction: w0->A, w1->B; w2+=A, w3+=B ----
        float* OrA = (float*)smem;               // 32 x 68 f32
        float* OrB = OrA + 32 * 68;
        __syncthreads();
        if (w < 2) {
            float* R = (w == 0) ? OrA : OrB;
            #pragma unroll
            for (int qg = 0; qg < 2; ++qg)
                #pragma unroll
                for (int i = 0; i < 4; ++i) {
                    const int row = qg * 16 + quad * 4 + i;
                    #pragma unroll
                    for (int db = 0; db < 4; ++db)
                        R[row * 68 + db * 16 + col] = O[qg][db][i];
                    if (col == 0) R[row * 68 + 64] = L4[qg][i];
                }
        }
        __syncthreads();
        if (w >= 2) {
            float* R = (w == 2) ? OrA : OrB;
            #pragma unroll
            for (int qg = 0; qg < 2; ++qg)
                #pragma unroll
                for (int i = 0; i < 4; ++i) {
                    const int row = qg * 16 + quad * 4 + i;
                    #pragma unroll
                    for (int db = 0; db < 4; ++db)
                        R[row * 68 + db * 16 + col] += O[qg][db][i];
                    if (col == 0) R[row * 68 + 64] += L4[qg][i];
                }
        }
        __syncthreads();

        // ---- combine A+B, normalize, store: wave w -> rows [w*8, w*8+8) ----
        #pragma unroll
        for (int rstep = 0; rstep < 2; ++rstep) {
            const int row = w * 8 + rstep * 4 + quad;
            f32x4 oa = *(const f32x4*)&OrA[row * 68 + col * 4];
            f32x4 ob = *(const f32x4*)&OrB[row * 68 + col * 4];
            const float inv = 1.f / (OrA[row * 68 + 64] + OrB[row * 68 + 64]);
            int2v o2 = { pack2bf((oa[0] + ob[0]) * inv, (oa[1] + ob[1]) * inv),
                         pack2bf((oa[2] + ob[2]) * inv, (oa[3] + ob[3]) * inv) };
            *(int2v*)(y + ((size_t)b * K + t0 + row) * C + h * DH + col * 4) = o2;
        }
        __syncthreads();   // protect Or/P alias before next tile restages
    };

    run(g);
    run(63 - g);
}

// ------------------------------- launch -------------------------------------
extern "C" void kernel_launch(void* const* d_in, const int* in_sizes, int n_in,
                              void* d_out, int out_size, void* d_ws, size_t ws_size,
                              hipStream_t stream)
{
    const float* x      = (const float*)d_in[0];
    const float* W_qkv  = (const float*)d_in[1];
    const float* b_qkv  = (const float*)d_in[2];
    const float* W_proj = (const float*)d_in[3];
    const float* b_proj = (const float*)d_in[4];

    const int B = 2, K = 2048, C = 1024, H = 16;
    const int M = B * K;   // 4096
    const float C2 = 0.18033688f;   // (1/sqrt(64)) * log2(e)

    char* ws = (char*)d_ws;
    short* xb    = (short*)ws;  ws += (size_t)M * C * 2;
    short* Wt1   = (short*)ws;  ws += (size_t)3 * C * C * 2;
    short* Wt2   = (short*)ws;  ws += (size_t)C * C * 2;
    short* qb    = (short*)ws;  ws += (size_t)M * C * 2;
    short* yb    = (short*)ws;  ws += (size_t)M * C * 2;
    short* kvp   = (short*)ws;  // 32 bh x 64 ci x 8 frag x 512 sh = 16.8 MB

    // prep (fused): cast x + transpose both weights
    const int nbx = (M * C) / 1024;
    const int nb1 = (3 * C / 32) * (C / 32);
    const int nb2 = (C / 32) * (C / 32);
    prep_kernel<<<nbx + nb1 + nb2, 256, 0, stream>>>(x, xb, M * C, W_qkv, Wt1, W_proj, Wt2, C);

    // 1) fused qkv GEMM: Q -> qb (pre-scaled), K/V -> kvp (fragment-packed)
    //    768 blocks = 3 blocks/CU; kvpack kernel eliminated
    dim3 g1((3 * C) / 128, M / 128);
    gemm_qkv_kernel<<<g1, 256, 0, stream>>>(xb, Wt1, b_qkv, qb, kvp, M, 3 * C, C, C, K, C2);

    // 2) flash attention -> yb (bf16); 1-D grid: idx = pair*32 + (b*16+h)
    //    32 pair-balanced 32-q tile-pairs x 32 bh = 1024 blocks (4/CU exact)
    flash_mfma_kernel<<<dim3(32 * 32), 256, 0, stream>>>(qb, kvp, yb, K, C);

    // 3) out = y @ W_proj + b_proj (fp32 out); 128x64 tile: 512 blocks = 2/CU
    dim3 g3(C / 64, M / 128);
    gemm_mfma_kernel<float, 128, 64><<<g3, 256, 0, stream>>>(yb, Wt2, b_proj, (float*)d_out, M, C, C);
}

// Round 10
// 171.587 us; speedup vs baseline: 1.0890x; 1.0890x over previous
//
#include <hip/hip_runtime.h>
#include <hip/hip_bf16.h>
#include <math.h>

typedef __attribute__((ext_vector_type(8))) short short8;
typedef __attribute__((ext_vector_type(4))) float f32x4;
typedef __attribute__((ext_vector_type(4))) short short4v;
typedef __attribute__((ext_vector_type(2))) int int2v;

static __device__ __forceinline__ short f2bf(float f) {
    __hip_bfloat16 h = __float2bfloat16(f);
    return *reinterpret_cast<short*>(&h);
}
static __device__ __forceinline__ void store_out(float* p, float v) { *p = v; }
static __device__ __forceinline__ void store_out(short* p, float v) { *p = f2bf(v); }

#define GLL16(g, l) __builtin_amdgcn_global_load_lds( \
    (const __attribute__((address_space(1))) void*)(g), \
    (__attribute__((address_space(3))) void*)(l), 16, 0, 0)

#if __has_builtin(__builtin_amdgcn_exp2f)
#define EXP2(x) __builtin_amdgcn_exp2f(x)
#else
#define EXP2(x) exp2f(x)
#endif

// pack two f32 -> packed bf16 pair (low = a, high = b)
#if __has_builtin(__builtin_amdgcn_cvt_pk_bf16_f32)
typedef __attribute__((ext_vector_type(2))) __bf16 bf16x2;
static __device__ __forceinline__ int pack2bf(float a, float b) {
    bf16x2 r = __builtin_amdgcn_cvt_pk_bf16_f32(a, b);
    return __builtin_bit_cast(int, r);
}
#else
static __device__ __forceinline__ int pack2bf(float a, float b) {
    unsigned ua = __builtin_bit_cast(unsigned, a) + 0x8000u;
    unsigned ub = __builtin_bit_cast(unsigned, b) + 0x8000u;
    return (int)((ua >> 16) | (ub & 0xFFFF0000u));
}
#endif

// ---------------- fused prep: cast x -> bf16; transpose+cast both weights ----
static __device__ __forceinline__ void transpose_cast_tile(
    const float* __restrict__ W, short* __restrict__ Wt, int Kd, int N,
    int bx, int by)
{
    __shared__ float ts[32][33];
    const int c0 = bx * 32, r0 = by * 32;
    const int tx = threadIdx.x & 31, ty = threadIdx.x >> 5;   // ty 0..7
    #pragma unroll
    for (int e = 0; e < 4; ++e)
        ts[ty + e * 8][tx] = W[(size_t)(r0 + ty + e * 8) * N + c0 + tx];
    __syncthreads();
    #pragma unroll
    for (int e = 0; e < 4; ++e)
        Wt[(size_t)(c0 + ty + e * 8) * Kd + r0 + tx] = f2bf(ts[tx][ty + e * 8]);
}

__global__ __launch_bounds__(256) void prep_kernel(
    const float* __restrict__ x,      short* __restrict__ xb,    int nx,
    const float* __restrict__ W_qkv,  short* __restrict__ Wt1,
    const float* __restrict__ W_proj, short* __restrict__ Wt2,
    int C)
{
    const int nbx = nx / 1024;
    const int nb1 = (3 * C / 32) * (C / 32);
    int bid = blockIdx.x;
    if (bid < nbx) {
        int i = (bid * 256 + threadIdx.x) * 4;
        float4 v = *(const float4*)(x + i);
        short4v o = { f2bf(v.x), f2bf(v.y), f2bf(v.z), f2bf(v.w) };
        *(short4v*)(xb + i) = o;
        return;
    }
    bid -= nbx;
    if (bid < nb1) {
        const int nc = 3 * C / 32;
        transpose_cast_tile(W_qkv, Wt1, C, 3 * C, bid % nc, bid / nc);
        return;
    }
    bid -= nb1;
    {
        const int nc = C / 32;
        transpose_cast_tile(W_proj, Wt2, C, C, bid % nc, bid / nc);
    }
}

// ---------------- fused QKV GEMM + fragment-pack epilogue --------------------
// Round-10 changes (counters finally unmasked this kernel: MfmaUtil 18.5%,
// 3.3M LDS bank conflicts):
//   - V-staging writes VECTORIZED: each (mt,nt) packs its 4 contiguous-rr
//     values into one 8B short4 write (16 vec writes vs 64 scalar/thread) --
//     the scalar feat-major scatter was the bulk of the 3.3M conflicts.
//   - XCD-chunked blockIdx swizzle (T1; 768%8==0 bijective): consecutive
//     A-row-sharing tiles land on ONE XCD's L2 instead of round-robining
//     across all 8 -> A-panel reuse in L2.
// Otherwise round-7/8 proven form: Q -> dense qb scaled bf16; K/V staged in
// LDS (K token-major scalar, V feat-major vec), fragment-packed kvp out.
// kvp[bh][ci][f][lane*8sh], f 0..3 = K(nb*2+half), f 4..7 = V(db).
#define GK 32

__global__ __launch_bounds__(256) void gemm_qkv_kernel(
    const short* __restrict__ A, const short* __restrict__ Bt,
    const float* __restrict__ bias,
    short* __restrict__ qb, short* __restrict__ kvp,
    int M, int N, int Kd, int C, int Ktok, float qscale)
{
    __shared__ __attribute__((aligned(16))) short smem[17408];  // 34.8KB union
    short* As = smem;            // [128*32], K-loop only
    short* Bs = smem + 4096;     // [128*32], K-loop only
    short* T  = smem;            // [128][136] epilogue staging (after barrier)

    const int tid  = threadIdx.x;
    const int lane = tid & 63, w = tid >> 6;
    const int col  = lane & 15, quad = lane >> 4;
    const int wm = (w & 1) * 64, wn = (w >> 1) * 64;

    // XCD-chunked swizzle (bijective: nwg % 8 == 0)
    const int nwg  = gridDim.x * gridDim.y;
    const int bid0 = blockIdx.y * gridDim.x + blockIdx.x;
    const int bid  = (bid0 & 7) * (nwg >> 3) + (bid0 >> 3);
    const int row0 = (bid / gridDim.x) * 128, col0 = (bid % gridDim.x) * 128;

    const int sr = tid >> 2, scg = (tid & 3) * 8;
    const short* gA = A  + (size_t)(row0 + sr) * Kd + scg;
    const short* gB = Bt + (size_t)(col0 + sr) * Kd + scg;
    short* lA = As + sr * GK + scg;
    short* lB = Bs + sr * GK + scg;
    const size_t skip = (size_t)64 * Kd;

    f32x4 acc[4][4] = {};
    for (int k0 = 0; k0 < Kd; k0 += GK) {
        __syncthreads();
        GLL16(gA,        lA);
        GLL16(gA + skip, lA + 64 * GK);
        GLL16(gB,        lB);
        GLL16(gB + skip, lB + 64 * GK);
        gA += GK; gB += GK;
        __syncthreads();

        short8 aF[4], bF[4];
        #pragma unroll
        for (int mt = 0; mt < 4; ++mt)
            aF[mt] = *(const short8*)&As[(wm + mt * 16 + col) * GK + quad * 8];
        #pragma unroll
        for (int nt = 0; nt < 4; ++nt)
            bF[nt] = *(const short8*)&Bs[(wn + nt * 16 + col) * GK + quad * 8];
        #pragma unroll
        for (int mt = 0; mt < 4; ++mt)
            #pragma unroll
            for (int nt = 0; nt < 4; ++nt)
                acc[mt][nt] = __builtin_amdgcn_mfma_f32_16x16x32_bf16(aF[mt], bF[nt], acc[mt][nt], 0, 0, 0);
    }

    if (col0 < C) {
        // ---- Q epilogue: scaled bf16 -> dense qb[M][C] ----
        #pragma unroll
        for (int mt = 0; mt < 4; ++mt)
            #pragma unroll
            for (int i = 0; i < 4; ++i) {
                const size_t r = row0 + wm + mt * 16 + quad * 4 + i;
                #pragma unroll
                for (int nt = 0; nt < 4; ++nt) {
                    const int c = col0 + wn + nt * 16 + col;
                    qb[r * C + c] = f2bf((acc[mt][nt][i] + bias[c]) * qscale);
                }
            }
        return;
    }

    // ---- K/V epilogue: stage tile in LDS, emit fragment-packed kvp ----
    const bool isK = col0 < 2 * C;
    __syncthreads();                         // all waves done with As/Bs
    #pragma unroll
    for (int mt = 0; mt < 4; ++mt) {
        const int rr0 = wm + mt * 16 + quad * 4;
        #pragma unroll
        for (int nt = 0; nt < 4; ++nt) {
            const int cr = wn + nt * 16 + col;           // feat_rel
            const float bb_ = bias[col0 + cr];
            if (isK) {                                   // token-major scalar
                #pragma unroll
                for (int i = 0; i < 4; ++i)
                    T[(rr0 + i) * 136 + cr] = f2bf(acc[mt][nt][i] + bb_);
            } else {                                     // feat-major VEC (8B)
                short4v pk = { f2bf(acc[mt][nt][0] + bb_),
                               f2bf(acc[mt][nt][1] + bb_),
                               f2bf(acc[mt][nt][2] + bb_),
                               f2bf(acc[mt][nt][3] + bb_) };
                *(short4v*)&T[cr * 136 + rr0] = pk;
            }
        }
    }
    __syncthreads();

    const int bb  = row0 / Ktok, k0t = row0 % Ktok;
    const int h0  = (col0 - (isK ? C : 2 * C)) >> 6;         // 2 heads/block
    #pragma unroll
    for (int j = 0; j < 8; ++j) {
        const int s     = tid + j * 256;                     // 0..2047
        const int lane2 = s & 63, f = (s >> 6) & 3, cil = (s >> 8) & 3, hl = s >> 10;
        const int col2  = lane2 & 15, quad2 = lane2 >> 4;
        short8 d;
        if (isK) {   // K frag f=nb*2+half: K[2*col2+nb][half*32+quad2*8 ..+8]
            const int nb = f >> 1, half = f & 1;
            d = *(const short8*)&T[(cil * 32 + 2 * col2 + nb) * 136
                                   + hl * 64 + half * 32 + quad2 * 8];
        } else {     // V frag f=db: V[quad2*8+j'][db*16+col2] via transposed T
            d = *(const short8*)&T[(hl * 64 + f * 16 + col2) * 136
                                   + cil * 32 + quad2 * 8];
        }
        const int bh = bb * 16 + h0 + hl;
        const int ci = (k0t >> 5) + cil;
        const int fr = isK ? f : 4 + f;
        *(short8*)(kvp + (((size_t)bh * 64 + ci) * 8 + fr) * 512 + lane2 * 8) = d;
    }
}

// ---------------- MFMA bf16 GEMM (m97 structure): C = A @ Bt^T + bias --------
// Templated on tile (GM x GN). gemm3 at 128x64 -> 512 blocks = 2/CU (round 5).
// Round-10: XCD-chunked swizzle (512%8==0 bijective) for A-panel L2 reuse.
template <typename OutT, int GM, int GN>
__global__ __launch_bounds__(256) void gemm_mfma_kernel(
    const short* __restrict__ A, const short* __restrict__ Bt,
    const float* __restrict__ bias, OutT* __restrict__ C,
    int M, int N, int Kd)
{
    constexpr int WM = GM / 2, WN = GN / 2;      // per-wave quadrant
    __shared__ __attribute__((aligned(16))) short As[GM * GK];
    __shared__ __attribute__((aligned(16))) short Bs[GN * GK];
    const int tid  = threadIdx.x;
    const int lane = tid & 63, w = tid >> 6;
    const int col  = lane & 15, quad = lane >> 4;
    const int wm = (w & 1) * WM, wn = (w >> 1) * WN;

    const int nwg  = gridDim.x * gridDim.y;
    const int bid0 = blockIdx.y * gridDim.x + blockIdx.x;
    const int bid  = (bid0 & 7) * (nwg >> 3) + (bid0 >> 3);
    const int row0 = (bid / gridDim.x) * GM, col0 = (bid % gridDim.x) * GN;

    const int sr = tid >> 2, scg = (tid & 3) * 8;   // 256 threads cover 64 rows x GK
    const short* gA = A  + (size_t)(row0 + sr) * Kd + scg;
    const short* gB = Bt + (size_t)(col0 + sr) * Kd + scg;
    short* lA = As + sr * GK + scg;
    short* lB = Bs + sr * GK + scg;
    const size_t skip = (size_t)64 * Kd;

    f32x4 acc[WM / 16][WN / 16] = {};
    for (int k0 = 0; k0 < Kd; k0 += GK) {
        __syncthreads();
        #pragma unroll
        for (int t = 0; t < GM / 64; ++t) GLL16(gA + t * skip, lA + t * 64 * GK);
        #pragma unroll
        for (int t = 0; t < GN / 64; ++t) GLL16(gB + t * skip, lB + t * 64 * GK);
        gA += GK; gB += GK;
        __syncthreads();

        short8 aF[WM / 16], bF[WN / 16];
        #pragma unroll
        for (int mt = 0; mt < WM / 16; ++mt)
            aF[mt] = *(const short8*)&As[(wm + mt * 16 + col) * GK + quad * 8];
        #pragma unroll
        for (int nt = 0; nt < WN / 16; ++nt)
            bF[nt] = *(const short8*)&Bs[(wn + nt * 16 + col) * GK + quad * 8];
        #pragma unroll
        for (int mt = 0; mt < WM / 16; ++mt)
            #pragma unroll
            for (int nt = 0; nt < WN / 16; ++nt)
                acc[mt][nt] = __builtin_amdgcn_mfma_f32_16x16x32_bf16(aF[mt], bF[nt], acc[mt][nt], 0, 0, 0);
    }

    #pragma unroll
    for (int mt = 0; mt < WM / 16; ++mt)
        #pragma unroll
        for (int i = 0; i < 4; ++i) {
            const size_t r = row0 + wm + mt * 16 + quad * 4 + i;
            #pragma unroll
            for (int nt = 0; nt < WN / 16; ++nt) {
                const int c = col0 + wn + nt * 16 + col;
                store_out(&C[r * N + c], acc[mt][nt][i] + bias[c]);
            }
        }
}

// ---------------- MFMA flash attention — 32-q tiles, 4 waves/SIMD ------------
// ROUND-8 VERBATIM (best measured total, 177.0us; VGPR 120, no demotion).
// Round-9's K-prefetch variant regressed the total ~10us (and/or perturbed
// gemm_qkv's codegen, rule #19) -> reverted per pre-commitment. Three
// attempts at in-loop register pipelining all failed on this compiler;
// this axis is closed.
#define DH 64

__global__ __launch_bounds__(256, 4) void flash_mfma_kernel(
    const short* __restrict__ qb,     // bf16 [B*K][C] Q only (pre-scaled)
    const short* __restrict__ kvp,    // fragment-packed K/V
    short* __restrict__ y,            // bf16 [B,K,C]
    int K, int C)
{
    // Or region (2 x 32 x 68 f32 = 17408B) aliases the P region (5120 sh):
    // P is live only during the chunk loop, Or only after the __syncthreads().
    __shared__ __attribute__((aligned(16))) short smem[8704];

    const int tid  = threadIdx.x;
    const int lane = tid & 63, w = tid >> 6;
    const int col  = lane & 15, quad = lane >> 4;

    short* Pw = smem + w * 1280;           // 2 qg bufs x 640 sh, wave-private

    const int cmb = blockIdx.x & 31;       // b*16+h  (XCD-local: idx%8 tracks h)
    const int g   = blockIdx.x >> 5;       // pair index 0..31
    const int b   = cmb >> 4, h = cmb & 15;

    short8 bOnes;                          // L = P @ ones-column = rowsum
    #pragma unroll
    for (int j = 0; j < 8; ++j) bOnes[j] = (col == 0) ? (short)0x3F80 : (short)0;

    const short* qbase  = qb + (size_t)b * K * C + h * DH;
    const short* kvbase = kvp + (size_t)cmb * 64 * 4096 + lane * 8;

    struct Frag { short8 k[2][2]; short8 v[4]; };
    auto loadF = [&](Frag& f, int ci) {
        const short* p = kvbase + (size_t)ci * 4096;
        f.k[0][0] = *(const short8*)(p);
        f.k[0][1] = *(const short8*)(p + 512);
        f.k[1][0] = *(const short8*)(p + 1024);
        f.k[1][1] = *(const short8*)(p + 1536);
        f.v[0]    = *(const short8*)(p + 2048);
        f.v[1]    = *(const short8*)(p + 2560);
        f.v[2]    = *(const short8*)(p + 3072);
        f.v[3]    = *(const short8*)(p + 3584);
    };

    auto run = [&](int T) {
        const int t0 = T * 32;
        const int NC = T + 1;              // 32-key chunks in this tile

        short8 aQ[2][2];
        #pragma unroll
        for (int qg = 0; qg < 2; ++qg) {
            const short* qp = qbase + (size_t)(t0 + qg * 16 + col) * C;
            aQ[qg][0] = *(const short8*)(qp + quad * 8);
            aQ[qg][1] = *(const short8*)(qp + 32 + quad * 8);
        }
        f32x4 O[2][4] = {};
        f32x4 L4[2] = {};

        for (int ci = w; ci < NC; ci += 4) {
            Frag f;
            loadF(f, ci);
            const int kc = ci * 32;
            __builtin_amdgcn_s_setprio(1);
            #pragma unroll
            for (int qg = 0; qg < 2; ++qg) {
                const int qb2 = t0 + qg * 16;
                short* Ptq = Pw + qg * 640;            // private per (wave,qg)
                f32x4 S[2] = {};
                #pragma unroll
                for (int nb = 0; nb < 2; ++nb) {
                    S[nb] = __builtin_amdgcn_mfma_f32_16x16x32_bf16(aQ[qg][0], f.k[nb][0], S[nb], 0, 0, 0);
                    S[nb] = __builtin_amdgcn_mfma_f32_16x16x32_bf16(aQ[qg][1], f.k[nb][1], S[nb], 0, 0, 0);
                }
                if (kc + 31 <= qb2) {       // fully unmasked for this q-group
                    #pragma unroll
                    for (int i = 0; i < 4; ++i)
                        *(int*)&Ptq[(quad * 4 + i) * 40 + col * 2] =
                            pack2bf(EXP2(S[0][i]), EXP2(S[1][i]));
                } else {
                    const int kg = kc + col * 2;
                    #pragma unroll
                    for (int i = 0; i < 4; ++i) {
                        const int q = qb2 + quad * 4 + i;
                        float s0 = (kg + 0 <= q) ? S[0][i] : -INFINITY;
                        float s1 = (kg + 1 <= q) ? S[1][i] : -INFINITY;
                        *(int*)&Ptq[(quad * 4 + i) * 40 + col * 2] =
                            pack2bf(EXP2(s0), EXP2(s1));
                    }
                }
                // compiler inserts the minimal lgkmcnt for this buffer's RAW
                short8 aP = *(const short8*)&Ptq[col * 40 + quad * 8];
                #pragma unroll
                for (int db = 0; db < 4; ++db)
                    O[qg][db] = __builtin_amdgcn_mfma_f32_16x16x32_bf16(aP, f.v[db], O[qg][db], 0, 0, 0);
                L4[qg] = __builtin_amdgcn_mfma_f32_16x16x32_bf16(aP, bOnes, L4[qg], 0, 0, 0);
            }
            __builtin_amdgcn_s_setprio(0);
        }

        // ---- pairwise cross-wave reduction: w0->A, w1->B; w2+=A, w3+=B ----
        float* OrA = (float*)smem;               // 32 x 68 f32
        float* OrB = OrA + 32 * 68;
        __syncthreads();
        if (w < 2) {
            float* R = (w == 0) ? OrA : OrB;
            #pragma unroll
            for (int qg = 0; qg < 2; ++qg)
                #pragma unroll
                for (int i = 0; i < 4; ++i) {
                    const int row = qg * 16 + quad * 4 + i;
                    #pragma unroll
                    for (int db = 0; db < 4; ++db)
                        R[row * 68 + db * 16 + col] = O[qg][db][i];
                    if (col == 0) R[row * 68 + 64] = L4[qg][i];
                }
        }
        __syncthreads();
        if (w >= 2) {
            float* R = (w == 2) ? OrA : OrB;
            #pragma unroll
            for (int qg = 0; qg < 2; ++qg)
                #pragma unroll
                for (int i = 0; i < 4; ++i) {
                    const int row = qg * 16 + quad * 4 + i;
                    #pragma unroll
                    for (int db = 0; db < 4; ++db)
                        R[row * 68 + db * 16 + col] += O[qg][db][i];
                    if (col == 0) R[row * 68 + 64] += L4[qg][i];
                }
        }
        __syncthreads();

        // ---- combine A+B, normalize, store: wave w -> rows [w*8, w*8+8) ----
        #pragma unroll
        for (int rstep = 0; rstep < 2; ++rstep) {
            const int row = w * 8 + rstep * 4 + quad;
            f32x4 oa = *(const f32x4*)&OrA[row * 68 + col * 4];
            f32x4 ob = *(const f32x4*)&OrB[row * 68 + col * 4];
            const float inv = 1.f / (OrA[row * 68 + 64] + OrB[row * 68 + 64]);
            int2v o2 = { pack2bf((oa[0] + ob[0]) * inv, (oa[1] + ob[1]) * inv),
                         pack2bf((oa[2] + ob[2]) * inv, (oa[3] + ob[3]) * inv) };
            *(int2v*)(y + ((size_t)b * K + t0 + row) * C + h * DH + col * 4) = o2;
        }
        __syncthreads();   // protect Or/P alias before next tile restages
    };

    run(g);
    run(63 - g);
}

// ------------------------------- launch -------------------------------------
extern "C" void kernel_launch(void* const* d_in, const int* in_sizes, int n_in,
                              void* d_out, int out_size, void* d_ws, size_t ws_size,
                              hipStream_t stream)
{
    const float* x      = (const float*)d_in[0];
    const float* W_qkv  = (const float*)d_in[1];
    const float* b_qkv  = (const float*)d_in[2];
    const float* W_proj = (const float*)d_in[3];
    const float* b_proj = (const float*)d_in[4];

    const int B = 2, K = 2048, C = 1024, H = 16;
    const int M = B * K;   // 4096
    const float C2 = 0.18033688f;   // (1/sqrt(64)) * log2(e)

    char* ws = (char*)d_ws;
    short* xb    = (short*)ws;  ws += (size_t)M * C * 2;
    short* Wt1   = (short*)ws;  ws += (size_t)3 * C * C * 2;
    short* Wt2   = (short*)ws;  ws += (size_t)C * C * 2;
    short* qb    = (short*)ws;  ws += (size_t)M * C * 2;
    short* yb    = (short*)ws;  ws += (size_t)M * C * 2;
    short* kvp   = (short*)ws;  // 32 bh x 64 ci x 8 frag x 512 sh = 16.8 MB

    // prep (fused): cast x + transpose both weights
    const int nbx = (M * C) / 1024;
    const int nb1 = (3 * C / 32) * (C / 32);
    const int nb2 = (C / 32) * (C / 32);
    prep_kernel<<<nbx + nb1 + nb2, 256, 0, stream>>>(x, xb, M * C, W_qkv, Wt1, W_proj, Wt2, C);

    // 1) fused qkv GEMM: Q -> qb (pre-scaled), K/V -> kvp (fragment-packed)
    //    768 blocks = 3 blocks/CU; XCD-swizzled
    dim3 g1((3 * C) / 128, M / 128);
    gemm_qkv_kernel<<<g1, 256, 0, stream>>>(xb, Wt1, b_qkv, qb, kvp, M, 3 * C, C, C, K, C2);

    // 2) flash attention -> yb (bf16); 1-D grid: idx = pair*32 + (b*16+h)
    //    32 pair-balanced 32-q tile-pairs x 32 bh = 1024 blocks (4/CU exact)
    flash_mfma_kernel<<<dim3(32 * 32), 256, 0, stream>>>(qb, kvp, yb, K, C);

    // 3) out = y @ W_proj + b_proj (fp32 out); 128x64 tile: 512 blocks = 2/CU
    dim3 g3(C / 64, M / 128);
    gemm_mfma_kernel<float, 128, 64><<<g3, 256, 0, stream>>>(yb, Wt2, b_proj, (float*)d_out, M, C, C);
}